// Round 7
// baseline (83.642 us; speedup 1.0000x reference)
//
#include <hip/hip_runtime.h>
#include <hip/hip_bf16.h>

#define IN_CAPS 32
#define OUT_CAPS 10
#define NOUT 160      // OUT_CAPS*OUT_DIM
#define KDIM 288
#define BATCH 4096
#define KSTEPS 9      // 288/32
#define CTILES 10     // 160/16
#define STR2 162      // LDS ushort stride for u rows in routing

typedef __bf16 bf16x8 __attribute__((ext_vector_type(8)));
typedef float  f32x4  __attribute__((ext_vector_type(4)));
typedef __attribute__((address_space(1))) void as1_t;
typedef __attribute__((address_space(3))) void as3_t;

// ---------------------------------------------------------------------------
// prep_w: W f32 [32][288][160] -> bf16 in per-lane MFMA B-fragment order:
//   Wf[((n*9+ks)*10+ct)*512 + lane*8 + j] = W[n][ks*32+(lane>>4)*8+j][ct*16+(lane&15)]
// ---------------------------------------------------------------------------
__global__ __launch_bounds__(256) void prep_w(const float* __restrict__ W,
                                              __bf16* __restrict__ Wf) {
    int f = blockIdx.x * 256 + threadIdx.x;   // grid covers exactly 32*9*10*512
    int j    = f & 7;
    int l    = (f >> 3) & 63;
    int rest = f >> 9;
    int c    = rest % CTILES;
    int tnk  = rest / CTILES;
    int ks   = tnk % KSTEPS;
    int n    = tnk / KSTEPS;
    int k    = ks * 32 + (l >> 4) * 8 + j;
    int col  = c * 16 + (l & 15);
    Wf[f] = (__bf16)W[(n * KDIM + k) * NOUT + col];
}

// wave-uniform counted vmcnt wait (values used: 0,4,5,8,10)
__device__ __forceinline__ void waitv(int n) {
    switch (n) {
        case 0:  asm volatile("s_waitcnt vmcnt(0)"  ::: "memory"); break;
        case 4:  asm volatile("s_waitcnt vmcnt(4)"  ::: "memory"); break;
        case 5:  asm volatile("s_waitcnt vmcnt(5)"  ::: "memory"); break;
        case 8:  asm volatile("s_waitcnt vmcnt(8)"  ::: "memory"); break;
        default: asm volatile("s_waitcnt vmcnt(10)" ::: "memory"); break;
    }
}

// ---------------------------------------------------------------------------
// gemm_u v6: counted-vmcnt pipeline (T3/T4), NO vmcnt-draining barriers.
//  - 4 LDS buffers (72KB), depth-3: stage(ks+3) issued post-barrier(ks).
//    Race-free: barrier(ks) => all waves done with compute(ks-1), and
//    (ks+3)&3 == (ks-1)&3 is only reused after that barrier.
//  - per-wave derived wait: stage = 5 glds/thread (w<2) else 4;
//    N = stage_cnt * stages_in_flight(2,1,0 at tail).
//  - raw s_barrier + asm memory fence: no vmcnt(0) drain per step (the R6
//    structural stall: 250cy compute vs 900cy latency, serialized 9x).
//  - cohort remap: n=blk&31, rb=blk>>5 -> resident blocks share one 2.3MB
//    caps slice (page/L3 locality); same-n blocks share an XCD (32%8==0).
// ---------------------------------------------------------------------------
__global__ __launch_bounds__(256) void gemm_u(const float* __restrict__ caps,
                                              const __bf16* __restrict__ Wf,
                                              uint4* __restrict__ up) {
    __shared__ float  As[4][64 * 32];     // 4 x 8 KB
    __shared__ __bf16 Bs[4][5120];        // 4 x 10 KB  => 72 KB total

    const int lin  = blockIdx.x;          // 0..2047
    const int n    = lin & 31;            // capsule
    const int rb   = lin >> 5;            // 64-row block, 0..63
    const int w    = threadIdx.x >> 6;
    const int lane = threadIdx.x & 63;
    const int lm   = lane & 15;
    const int lk   = lane >> 4;

    // A staging geometry (verified R6): slot s = w*128 + q*64 + lane,
    // local row r = s>>3, source chunk c = (s&7) ^ (r&7)
    const int sl0 = w * 128 + lane;
    const int sl1 = sl0 + 64;
    const int r0 = sl0 >> 3, r1 = sl1 >> 3;
    const int c0 = (sl0 & 7) ^ (r0 & 7);
    const int c1 = (sl1 & 7) ^ (r1 & 7);
    const float* ga0 = caps + ((size_t)(rb * 64 + r0) * IN_CAPS + n) * KDIM + c0 * 4;
    const float* ga1 = caps + ((size_t)(rb * 64 + r1) * IN_CAPS + n) * KDIM + c1 * 4;
    const __bf16* wb = Wf + (size_t)n * (KSTEPS * 5120);

#define STAGE(ks) do {                                                               \
    const int _bf = (ks) & 3;                                                        \
    __builtin_amdgcn_global_load_lds((const as1_t*)(ga0 + (ks) * 32),                \
                                     (as3_t*)&As[_bf][w * 512],        16, 0, 0);    \
    __builtin_amdgcn_global_load_lds((const as1_t*)(ga1 + (ks) * 32),                \
                                     (as3_t*)&As[_bf][w * 512 + 256],  16, 0, 0);    \
    __builtin_amdgcn_global_load_lds((const as1_t*)(wb + (size_t)(ks) * 5120 +       \
                                     (w * 2) * 512 + lane * 8),                      \
                                     (as3_t*)&Bs[_bf][(w * 2) * 512],  16, 0, 0);    \
    __builtin_amdgcn_global_load_lds((const as1_t*)(wb + (size_t)(ks) * 5120 +       \
                                     (w * 2 + 1) * 512 + lane * 8),                  \
                                     (as3_t*)&Bs[_bf][(w * 2 + 1) * 512], 16, 0, 0); \
    if (w < 2)                                                                       \
        __builtin_amdgcn_global_load_lds((const as1_t*)(wb + (size_t)(ks) * 5120 +   \
                                         (8 + w) * 512 + lane * 8),                  \
                                         (as3_t*)&Bs[_bf][(8 + w) * 512], 16, 0, 0); \
} while (0)

    f32x4 acc[CTILES];
#pragma unroll
    for (int ct = 0; ct < CTILES; ++ct) acc[ct] = (f32x4){0.f, 0.f, 0.f, 0.f};

    // read-side A: row w*16+lm, XOR-swizzled chunk positions (conflict-free)
    const int rl = w * 16 + lm;
    const int h0 = ((2 * lk)     ^ (lm & 7)) * 4;
    const int h1 = ((2 * lk + 1) ^ (lm & 7)) * 4;
    const int per_stage = (w < 2) ? 5 : 4;

    STAGE(0); STAGE(1); STAGE(2);

#pragma unroll
    for (int ks = 0; ks < KSTEPS; ++ks) {
        const int rem = (8 - ks) < 2 ? (8 - ks) : 2;   // stages allowed in flight
        waitv(per_stage * rem);
        __builtin_amdgcn_s_barrier();
        asm volatile("" ::: "memory");                 // pin LDS ops to post-barrier
        if (ks + 3 < KSTEPS) STAGE(ks + 3);

        const float*  Ac = As[ks & 3];
        const __bf16* Bc = Bs[ks & 3];
        f32x4 x0 = *(const f32x4*)&Ac[rl * 32 + h0];
        f32x4 x1 = *(const f32x4*)&Ac[rl * 32 + h1];
        bf16x8 a;
        a[0] = (__bf16)x0[0]; a[1] = (__bf16)x0[1];
        a[2] = (__bf16)x0[2]; a[3] = (__bf16)x0[3];
        a[4] = (__bf16)x1[0]; a[5] = (__bf16)x1[1];
        a[6] = (__bf16)x1[2]; a[7] = (__bf16)x1[3];

#pragma unroll
        for (int ct = 0; ct < CTILES; ++ct) {
            bf16x8 bfr = *(const bf16x8*)&Bc[ct * 512 + lane * 8];
            acc[ct] = __builtin_amdgcn_mfma_f32_16x16x32_bf16(a, bfr, acc[ct], 0, 0, 0);
        }
    }

    // epilogue: permuted coalesced store (layout shared with routing):
    //   idx = (((n*128 + rw)*2 + mt)*5 + p)*64 + lane
    const int rw = rb * 2 + (w >> 1);
    const int mt = w & 1;
    const size_t cbase = ((((size_t)n * 128 + rw) * 2 + mt) * 5) * 64 + lane;
#pragma unroll
    for (int p = 0; p < 5; ++p) {
        bf16x8 pk;
#pragma unroll
        for (int j = 0; j < 8; ++j)
            pk[j] = (__bf16)acc[2 * p + (j >> 2)][j & 3];
        up[cbase + (size_t)p * 64] = __builtin_bit_cast(uint4, pk);
    }
#undef STAGE
}

// ---------------------------------------------------------------------------
// routing (unchanged from R4-R6): 4 consecutive batch rows per block.
// ---------------------------------------------------------------------------
__global__ __launch_bounds__(256) void routing(const uint4* __restrict__ up,
                                               const float* __restrict__ bbias,
                                               float* __restrict__ out) {
    __shared__ __bf16 ul[4][IN_CAPS * STR2];      // 41472 B
    __shared__ float  bl[4][IN_CAPS * OUT_CAPS];
    __shared__ float  cs[4][IN_CAPS * OUT_CAPS];
    __shared__ float  ss[4][NOUT];
    __shared__ float  vs[4][NOUT];
    __shared__ float  scale_s[4][16];

    const int t  = threadIdx.x;
    const int b0 = blockIdx.x * 4;
    const int rw = b0 >> 5;
    const int mt = (b0 >> 4) & 1;
    const int lk = (b0 >> 2) & 3;

    for (int c = t; c < 2560; c += 256) {
        int n   = c / 80;
        int rem = c - n * 80;
        int p   = rem >> 4;
        int lm  = rem & 15;
        size_t idx = ((((size_t)n * 128 + rw) * 2 + mt) * 5 + p) * 64 + lk * 16 + lm;
        bf16x8 v = __builtin_bit_cast(bf16x8, up[idx]);
#pragma unroll
        for (int j = 0; j < 8; ++j) {
            int ct = 2 * p + (j >> 2);
            int rr = j & 3;
            ul[rr][n * STR2 + ct * 16 + lm] = v[j];
        }
    }
    const int grp = t >> 6;
    const int g   = t & 63;
    for (int pp = g; pp < IN_CAPS * OUT_CAPS; pp += 64) bl[grp][pp] = bbias[pp];
    __syncthreads();

    for (int it = 0; it < 4; ++it) {
        if (it > 0) {
            for (int pp = g; pp < IN_CAPS * OUT_CAPS; pp += 64) {
                int n = pp & 31;
                int o = pp >> 5;
                float a = 0.f;
#pragma unroll
                for (int d = 0; d < 16; ++d)
                    a += (float)ul[grp][n * STR2 + o * 16 + d] * vs[grp][o * 16 + d];
                bl[grp][n * 10 + o] += a;
            }
            __syncthreads();
        }
        if (g < IN_CAPS) {
            float m = bl[grp][g * 10];
#pragma unroll
            for (int o = 1; o < 10; ++o) m = fmaxf(m, bl[grp][g * 10 + o]);
            float e[10];
            float sum = 0.f;
#pragma unroll
            for (int o = 0; o < 10; ++o) { e[o] = __expf(bl[grp][g * 10 + o] - m); sum += e[o]; }
            float inv = 1.0f / sum;
#pragma unroll
            for (int o = 0; o < 10; ++o) cs[grp][g * 10 + o] = e[o] * inv;
        }
        __syncthreads();
        for (int p = g; p < NOUT; p += 64) {
            int o = p >> 4;
            float a = 0.f;
#pragma unroll
            for (int nn = 0; nn < IN_CAPS; ++nn)
                a += cs[grp][nn * 10 + o] * (float)ul[grp][nn * STR2 + p];
            ss[grp][p] = a;
        }
        __syncthreads();
        if (g < OUT_CAPS) {
            float sq = 0.f;
#pragma unroll
            for (int d = 0; d < 16; ++d) { float x = ss[grp][g * 16 + d]; sq += x * x; }
            scale_s[grp][g] = sq / ((1.0f + sq) * sqrtf(sq));
        }
        __syncthreads();
        for (int p = g; p < NOUT; p += 64) vs[grp][p] = scale_s[grp][p >> 4] * ss[grp][p];
        __syncthreads();
    }

    for (int p = g; p < NOUT; p += 64)
        out[(size_t)(b0 + grp) * NOUT + p] = vs[grp][p];
}

// ---------------------------------------------------------------------------
extern "C" void kernel_launch(void* const* d_in, const int* in_sizes, int n_in,
                              void* d_out, int out_size, void* d_ws, size_t ws_size,
                              hipStream_t stream) {
    const float* caps  = (const float*)d_in[0];   // [4096][32][288]
    const float* W     = (const float*)d_in[1];   // [32][288][160]
    const float* bbias = (const float*)d_in[2];   // [32][10]
    float* out = (float*)d_out;                   // [4096][10][16]

    __bf16* Wf = (__bf16*)d_ws;                               // 2,949,120 B
    uint4*  up = (uint4*)((char*)d_ws + 2949120);             // 41,943,040 B

    prep_w<<<dim3(5760), dim3(256), 0, stream>>>(W, Wf);
    gemm_u<<<dim3(2048), dim3(256), 0, stream>>>(caps, Wf, up);
    routing<<<dim3(BATCH / 4), dim3(256), 0, stream>>>(up, bbias, out);
}

// Round 8
// 79.762 us; speedup vs baseline: 1.0486x; 1.0486x over previous
//
#include <hip/hip_runtime.h>
#include <hip/hip_bf16.h>

#define IN_CAPS 32
#define OUT_CAPS 10
#define NOUT 160      // OUT_CAPS*OUT_DIM
#define KDIM 288
#define BATCH 4096
#define KSTEPS 9      // 288/32
#define CTILES 10     // 160/16
#define STR2 162      // LDS ushort stride for u rows in routing

typedef __bf16 bf16x8 __attribute__((ext_vector_type(8)));
typedef float  f32x4  __attribute__((ext_vector_type(4)));
typedef __attribute__((address_space(1))) void as1_t;
typedef __attribute__((address_space(3))) void as3_t;

// ---------------------------------------------------------------------------
// prep_w: W f32 [32][288][160] -> bf16 in per-lane MFMA B-fragment order:
//   Wf[((n*9+ks)*10+ct)*512 + lane*8 + j] = W[n][ks*32+(lane>>4)*8+j][ct*16+(lane&15)]
// ---------------------------------------------------------------------------
__global__ __launch_bounds__(256) void prep_w(const float* __restrict__ W,
                                              __bf16* __restrict__ Wf) {
    int f = blockIdx.x * 256 + threadIdx.x;   // grid covers exactly 32*9*10*512
    int j    = f & 7;
    int l    = (f >> 3) & 63;
    int rest = f >> 9;
    int c    = rest % CTILES;
    int tnk  = rest / CTILES;
    int ks   = tnk % KSTEPS;
    int n    = tnk / KSTEPS;
    int k    = ks * 32 + (l >> 4) * 8 + j;
    int col  = c * 16 + (l & 15);
    Wf[f] = (__bf16)W[(n * KDIM + k) * NOUT + col];
}

// wave-uniform counted vmcnt wait; called with unroll-constant n -> folds
__device__ __forceinline__ void waitv(int n) {
    switch (n) {
        case 0:  asm volatile("s_waitcnt vmcnt(0)"  ::: "memory"); break;
        case 2:  asm volatile("s_waitcnt vmcnt(2)"  ::: "memory"); break;
        case 4:  asm volatile("s_waitcnt vmcnt(4)"  ::: "memory"); break;
        case 6:  asm volatile("s_waitcnt vmcnt(6)"  ::: "memory"); break;
        case 9:  asm volatile("s_waitcnt vmcnt(9)"  ::: "memory"); break;
        default: asm volatile("s_waitcnt vmcnt(11)" ::: "memory"); break;
    }
}

// ---------------------------------------------------------------------------
// gemm_u v7: persistent-B, wave-private pipeline, ZERO barriers in main loop.
//  - 512-thread block owns one n; B panel (92 KB bf16, fragment order) copied
//    to LDS once, read-only thereafter. No per-step B staging (the R2-R7
//    residue: B transit per K-step capped pipeline depth).
//  - each wave owns 64 rows = 4 chunks x 16; private 4-slot A-ring (8 KB)
//    fed by global_load_lds; per-wave counted vmcnt (stores accounted via
//    FIFO arithmetic: waits 11/9/9 after each chunk's 5 global stores).
//  - 36 unrolled steps/wave, depth-3 in flight (6 KB/wave, 48 KB/CU) ->
//    enough MLP to ride the per-CU HBM share; waves drift freely.
//  - LDS 157,696 B -> exactly 1 block/CU, grid 256 = CU count.
// ---------------------------------------------------------------------------
__global__ __launch_bounds__(512) void gemm_u(const float* __restrict__ caps,
                                              const __bf16* __restrict__ Wf,
                                              uint4* __restrict__ up) {
    __shared__ float  As[8][4][512];      // 65,536 B: [wave][slot][16 rows x 32 f32]
    __shared__ __bf16 Bs[KSTEPS * 5120];  // 92,160 B

    const int lin  = blockIdx.x;          // 0..255
    const int n    = lin & 31;            // capsule
    const int rg   = lin >> 5;            // row-group 0..7 (512 rows each)
    const int w    = threadIdx.x >> 6;    // wave 0..7
    const int lane = threadIdx.x & 63;
    const int lm   = lane & 15;
    const int lk   = lane >> 4;

    // A-ring staging geometry (verified R6/R7): per glds q, slot sl=q*64+lane,
    // local row r = sl>>3, source chunk cc = (sl&7) ^ (r&7)  [XOR involution]
    const int r0  = lane >> 3;                    // rows 0..7 (q=0); q=1 adds 8
    const int cc0 = (lane & 7) ^ (r0 & 7);        // same for q=1 (r1&7 == r0&7)
    const int row0 = rg * 512 + w * 64;
    const float* g0 = caps + ((size_t)(row0 + r0)     * IN_CAPS + n) * KDIM + cc0 * 4;
    const float* g1 = caps + ((size_t)(row0 + 8 + r0) * IN_CAPS + n) * KDIM + cc0 * 4;

#define STAGE(s_) do {                                                            \
    const int c_ = (s_) / 9, k_ = (s_) % 9, sl_ = (s_) & 3;                       \
    const size_t off_ = (size_t)c_ * 16 * IN_CAPS * KDIM + k_ * 32;               \
    __builtin_amdgcn_global_load_lds((const as1_t*)(g0 + off_),                   \
                                     (as3_t*)&As[w][sl_][0],   16, 0, 0);         \
    __builtin_amdgcn_global_load_lds((const as1_t*)(g1 + off_),                   \
                                     (as3_t*)&As[w][sl_][256], 16, 0, 0);         \
} while (0)

    // start the A pipeline early, then copy B under its latency
    STAGE(0); STAGE(1); STAGE(2);

    const uint4* wsrc = (const uint4*)(Wf + (size_t)n * (KSTEPS * 5120));
    uint4* bdst = (uint4*)Bs;
    for (int i = threadIdx.x; i < KSTEPS * 5120 / 8; i += 512) bdst[i] = wsrc[i];
    __syncthreads();   // B visible to all waves (also drains prologue: harmless)

    f32x4 acc[CTILES];
#pragma unroll
    for (int ct = 0; ct < CTILES; ++ct) acc[ct] = (f32x4){0.f, 0.f, 0.f, 0.f};

    // read-side A: row lm of current chunk, XOR-swizzled chunk positions
    const int h0 = ((2 * lk)     ^ (lm & 7)) * 4;
    const int h1 = ((2 * lk + 1) ^ (lm & 7)) * 4;

#pragma unroll
    for (int s = 0; s < 36; ++s) {
        const int c_ = s / 9, k_ = s % 9;
        if (s + 3 < 36) STAGE(s + 3);

        // derived vmcnt: keep stages s+1..s+3 (2 glds each) in flight;
        // chunk-boundary stores (5) sit in the FIFO for ks=0..2 windows.
        int wn;
        if      (s >= 33)               wn = 2 * (35 - s);     // tail drain
        else if (c_ > 0 && k_ == 0)     wn = 11;
        else if (c_ > 0 && k_ <= 2)     wn = 9;
        else                            wn = 6;
        waitv(wn);

        const float* Ac = &As[w][s & 3][0];
        f32x4 x0 = *(const f32x4*)&Ac[lm * 32 + h0];
        f32x4 x1 = *(const f32x4*)&Ac[lm * 32 + h1];
        bf16x8 a;
        a[0] = (__bf16)x0[0]; a[1] = (__bf16)x0[1];
        a[2] = (__bf16)x0[2]; a[3] = (__bf16)x0[3];
        a[4] = (__bf16)x1[0]; a[5] = (__bf16)x1[1];
        a[6] = (__bf16)x1[2]; a[7] = (__bf16)x1[3];

        const __bf16* Bc = &Bs[k_ * 5120 + lane * 8];
#pragma unroll
        for (int ct = 0; ct < CTILES; ++ct) {
            bf16x8 bfr = *(const bf16x8*)(Bc + ct * 512);
            acc[ct] = __builtin_amdgcn_mfma_f32_16x16x32_bf16(a, bfr, acc[ct], 0, 0, 0);
        }

        if (k_ == 8) {
            // chunk done: permuted coalesced store (layout shared w/ routing):
            //   idx = (((n*128 + rw)*2 + mt)*5 + p)*64 + lane
            const int rw = rg * 16 + w * 2 + (c_ >> 1);
            const int mt = c_ & 1;
            const size_t cbase = ((((size_t)n * 128 + rw) * 2 + mt) * 5) * 64 + lane;
#pragma unroll
            for (int p = 0; p < 5; ++p) {
                bf16x8 pk;
#pragma unroll
                for (int j = 0; j < 8; ++j)
                    pk[j] = (__bf16)acc[2 * p + (j >> 2)][j & 3];
                up[cbase + (size_t)p * 64] = __builtin_bit_cast(uint4, pk);
            }
#pragma unroll
            for (int ct = 0; ct < CTILES; ++ct) acc[ct] = (f32x4){0.f, 0.f, 0.f, 0.f};
        }
    }
#undef STAGE
}

// ---------------------------------------------------------------------------
// routing (unchanged from R4-R7): 4 consecutive batch rows per block.
// ---------------------------------------------------------------------------
__global__ __launch_bounds__(256) void routing(const uint4* __restrict__ up,
                                               const float* __restrict__ bbias,
                                               float* __restrict__ out) {
    __shared__ __bf16 ul[4][IN_CAPS * STR2];      // 41472 B
    __shared__ float  bl[4][IN_CAPS * OUT_CAPS];
    __shared__ float  cs[4][IN_CAPS * OUT_CAPS];
    __shared__ float  ss[4][NOUT];
    __shared__ float  vs[4][NOUT];
    __shared__ float  scale_s[4][16];

    const int t  = threadIdx.x;
    const int b0 = blockIdx.x * 4;
    const int rw = b0 >> 5;
    const int mt = (b0 >> 4) & 1;
    const int lk = (b0 >> 2) & 3;

    for (int c = t; c < 2560; c += 256) {
        int n   = c / 80;
        int rem = c - n * 80;
        int p   = rem >> 4;
        int lm  = rem & 15;
        size_t idx = ((((size_t)n * 128 + rw) * 2 + mt) * 5 + p) * 64 + lk * 16 + lm;
        bf16x8 v = __builtin_bit_cast(bf16x8, up[idx]);
#pragma unroll
        for (int j = 0; j < 8; ++j) {
            int ct = 2 * p + (j >> 2);
            int rr = j & 3;
            ul[rr][n * STR2 + ct * 16 + lm] = v[j];
        }
    }
    const int grp = t >> 6;
    const int g   = t & 63;
    for (int pp = g; pp < IN_CAPS * OUT_CAPS; pp += 64) bl[grp][pp] = bbias[pp];
    __syncthreads();

    for (int it = 0; it < 4; ++it) {
        if (it > 0) {
            for (int pp = g; pp < IN_CAPS * OUT_CAPS; pp += 64) {
                int n = pp & 31;
                int o = pp >> 5;
                float a = 0.f;
#pragma unroll
                for (int d = 0; d < 16; ++d)
                    a += (float)ul[grp][n * STR2 + o * 16 + d] * vs[grp][o * 16 + d];
                bl[grp][n * 10 + o] += a;
            }
            __syncthreads();
        }
        if (g < IN_CAPS) {
            float m = bl[grp][g * 10];
#pragma unroll
            for (int o = 1; o < 10; ++o) m = fmaxf(m, bl[grp][g * 10 + o]);
            float e[10];
            float sum = 0.f;
#pragma unroll
            for (int o = 0; o < 10; ++o) { e[o] = __expf(bl[grp][g * 10 + o] - m); sum += e[o]; }
            float inv = 1.0f / sum;
#pragma unroll
            for (int o = 0; o < 10; ++o) cs[grp][g * 10 + o] = e[o] * inv;
        }
        __syncthreads();
        for (int p = g; p < NOUT; p += 64) {
            int o = p >> 4;
            float a = 0.f;
#pragma unroll
            for (int nn = 0; nn < IN_CAPS; ++nn)
                a += cs[grp][nn * 10 + o] * (float)ul[grp][nn * STR2 + p];
            ss[grp][p] = a;
        }
        __syncthreads();
        if (g < OUT_CAPS) {
            float sq = 0.f;
#pragma unroll
            for (int d = 0; d < 16; ++d) { float x = ss[grp][g * 16 + d]; sq += x * x; }
            scale_s[grp][g] = sq / ((1.0f + sq) * sqrtf(sq));
        }
        __syncthreads();
        for (int p = g; p < NOUT; p += 64) vs[grp][p] = scale_s[grp][p >> 4] * ss[grp][p];
        __syncthreads();
    }

    for (int p = g; p < NOUT; p += 64)
        out[(size_t)(b0 + grp) * NOUT + p] = vs[grp][p];
}

// ---------------------------------------------------------------------------
extern "C" void kernel_launch(void* const* d_in, const int* in_sizes, int n_in,
                              void* d_out, int out_size, void* d_ws, size_t ws_size,
                              hipStream_t stream) {
    const float* caps  = (const float*)d_in[0];   // [4096][32][288]
    const float* W     = (const float*)d_in[1];   // [32][288][160]
    const float* bbias = (const float*)d_in[2];   // [32][10]
    float* out = (float*)d_out;                   // [4096][10][16]

    __bf16* Wf = (__bf16*)d_ws;                               // 2,949,120 B
    uint4*  up = (uint4*)((char*)d_ws + 2949120);             // 41,943,040 B

    prep_w<<<dim3(5760), dim3(256), 0, stream>>>(W, Wf);
    gemm_u<<<dim3(256), dim3(512), 0, stream>>>(caps, Wf, up);
    routing<<<dim3(BATCH / 4), dim3(256), 0, stream>>>(up, bbias, out);
}

// Round 9
// 78.627 us; speedup vs baseline: 1.0638x; 1.0144x over previous
//
#include <hip/hip_runtime.h>
#include <hip/hip_bf16.h>

#define IN_CAPS 32
#define OUT_CAPS 10
#define NOUT 160      // OUT_CAPS*OUT_DIM
#define KDIM 288
#define BATCH 4096
#define KSTEPS 9      // 288/32
#define CTILES 10     // 160/16
#define STR2 162      // LDS ushort stride for u rows in routing

typedef __bf16 bf16x8 __attribute__((ext_vector_type(8)));
typedef float  f32x4  __attribute__((ext_vector_type(4)));

// ---------------------------------------------------------------------------
// prep_w: W f32 [32][288][160] -> bf16 in per-lane MFMA B-fragment order:
//   Wf[((n*9+ks)*10+ct)*512 + lane*8 + j] = W[n][ks*32+(lane>>4)*8+j][ct*16+(lane&15)]
// ---------------------------------------------------------------------------
__global__ __launch_bounds__(256) void prep_w(const float* __restrict__ W,
                                              __bf16* __restrict__ Wf) {
    int f = blockIdx.x * 256 + threadIdx.x;   // grid covers exactly 32*9*10*512
    int j    = f & 7;
    int l    = (f >> 3) & 63;
    int rest = f >> 9;
    int c    = rest % CTILES;
    int tnk  = rest / CTILES;
    int ks   = tnk % KSTEPS;
    int n    = tnk / KSTEPS;
    int k    = ks * 32 + (l >> 4) * 8 + j;
    int col  = c * 16 + (l & 15);
    Wf[f] = (__bf16)W[(n * KDIM + k) * NOUT + col];
}

// ---------------------------------------------------------------------------
// gemm_u v8: DISCRIMINATING EXPERIMENT — no global_load_lds anywhere in the
// K-loop, no LDS for A, no barriers in the K-loop.
//  - B panel (92 KB bf16, fragment order) copied to LDS once per block.
//  - A: pure reg staging, depth-3 ring of f32x4 loads (96 KB/CU in flight
//    through the normal vector-load path), compiler-scheduled waitcnt.
//  - 32 rows/wave, acc[2][10] = 80 VGPR, ~160 total (no launch_bounds force;
//    R3 lesson). 512 thr / 8 waves, 1 block/CU (92 KB LDS), grid 512.
//  - If glds-DMA was the wall -> 2x. If per-CU read wall/partition -> flat.
// ---------------------------------------------------------------------------
__global__ __launch_bounds__(512) void gemm_u(const float* __restrict__ caps,
                                              const __bf16* __restrict__ Wf,
                                              uint4* __restrict__ up) {
    __shared__ __bf16 Bs[KSTEPS * 5120];  // 92,160 B, loaded once

    const int lin  = blockIdx.x;          // 0..511, n-fastest (cohort shares rows)
    const int n    = lin & 31;
    const int rg   = lin >> 5;            // 256-row group, 0..15
    const int w    = threadIdx.x >> 6;    // wave 0..7
    const int lane = threadIdx.x & 63;
    const int lm   = lane & 15;
    const int lk   = lane >> 4;

    // ---- B panel: global -> LDS once (5760 uint4 over 512 threads) ----
    {
        const uint4* wsrc = (const uint4*)(Wf + (size_t)n * (KSTEPS * 5120));
        uint4* bdst = (uint4*)Bs;
#pragma unroll
        for (int i = 0; i < 11; ++i)
            bdst[threadIdx.x + i * 512] = wsrc[threadIdx.x + i * 512];
        if (threadIdx.x < 128) bdst[threadIdx.x + 11 * 512] = wsrc[threadIdx.x + 11 * 512];
    }

    // ---- A addressing: wave owns rows rg*256 + w*32 + {lm, 16+lm} ----
    const int row0 = rg * 256 + w * 32;
    const float* a0 = caps + ((size_t)(row0 + lm) * IN_CAPS + n) * KDIM + lk * 8;
    const float* a1 = a0 + (size_t)16 * IN_CAPS * KDIM;

    // depth-3 prefetch ring: pre[s%3][0..1] = rows lm / 16+lm, chunks 2lk,2lk+1
    f32x4 pre[3][4];
#pragma unroll
    for (int s = 0; s < 3; ++s) {
        pre[s][0] = *(const f32x4*)(a0 + s * 32);
        pre[s][1] = *(const f32x4*)(a0 + s * 32 + 4);
        pre[s][2] = *(const f32x4*)(a1 + s * 32);
        pre[s][3] = *(const f32x4*)(a1 + s * 32 + 4);
    }

    f32x4 acc[2][CTILES];
#pragma unroll
    for (int mt = 0; mt < 2; ++mt)
#pragma unroll
        for (int ct = 0; ct < CTILES; ++ct)
            acc[mt][ct] = (f32x4){0.f, 0.f, 0.f, 0.f};

    __syncthreads();   // B panel visible

#pragma unroll
    for (int ks = 0; ks < KSTEPS; ++ks) {
        // convert current stage (compiler waits only on these 4 loads)
        bf16x8 afr[2];
#pragma unroll
        for (int mt = 0; mt < 2; ++mt) {
            f32x4 x0 = pre[ks % 3][2 * mt];
            f32x4 x1 = pre[ks % 3][2 * mt + 1];
            bf16x8 a;
            a[0] = (__bf16)x0[0]; a[1] = (__bf16)x0[1];
            a[2] = (__bf16)x0[2]; a[3] = (__bf16)x0[3];
            a[4] = (__bf16)x1[0]; a[5] = (__bf16)x1[1];
            a[6] = (__bf16)x1[2]; a[7] = (__bf16)x1[3];
            afr[mt] = a;
        }
        // refill the ring for ks+3 (static slot index: (ks+3)%3 == ks%3)
        if (ks + 3 < KSTEPS) {
            pre[ks % 3][0] = *(const f32x4*)(a0 + (ks + 3) * 32);
            pre[ks % 3][1] = *(const f32x4*)(a0 + (ks + 3) * 32 + 4);
            pre[ks % 3][2] = *(const f32x4*)(a1 + (ks + 3) * 32);
            pre[ks % 3][3] = *(const f32x4*)(a1 + (ks + 3) * 32 + 4);
        }
        const __bf16* Bc = &Bs[ks * 5120 + lane * 8];
#pragma unroll
        for (int ct = 0; ct < CTILES; ++ct) {
            bf16x8 bfr = *(const bf16x8*)(Bc + ct * 512);
            acc[0][ct] = __builtin_amdgcn_mfma_f32_16x16x32_bf16(afr[0], bfr, acc[0][ct], 0, 0, 0);
            acc[1][ct] = __builtin_amdgcn_mfma_f32_16x16x32_bf16(afr[1], bfr, acc[1][ct], 0, 0, 0);
        }
    }

    // epilogue: permuted coalesced store (layout shared with routing):
    //   idx = (((n*128 + rw)*2 + mt)*5 + p)*64 + lane
    const int rw = (rg * 256 + w * 32) >> 5;   // 32-row unit
#pragma unroll
    for (int mt = 0; mt < 2; ++mt) {
        const size_t cbase = ((((size_t)n * 128 + rw) * 2 + mt) * 5) * 64 + lane;
#pragma unroll
        for (int p = 0; p < 5; ++p) {
            bf16x8 pk;
#pragma unroll
            for (int j = 0; j < 8; ++j)
                pk[j] = (__bf16)acc[mt][2 * p + (j >> 2)][j & 3];
            up[cbase + (size_t)p * 64] = __builtin_bit_cast(uint4, pk);
        }
    }
}

// ---------------------------------------------------------------------------
// routing (unchanged from R4-R8): 4 consecutive batch rows per block.
// ---------------------------------------------------------------------------
__global__ __launch_bounds__(256) void routing(const uint4* __restrict__ up,
                                               const float* __restrict__ bbias,
                                               float* __restrict__ out) {
    __shared__ __bf16 ul[4][IN_CAPS * STR2];      // 41472 B
    __shared__ float  bl[4][IN_CAPS * OUT_CAPS];
    __shared__ float  cs[4][IN_CAPS * OUT_CAPS];
    __shared__ float  ss[4][NOUT];
    __shared__ float  vs[4][NOUT];
    __shared__ float  scale_s[4][16];

    const int t  = threadIdx.x;
    const int b0 = blockIdx.x * 4;
    const int rw = b0 >> 5;
    const int mt = (b0 >> 4) & 1;
    const int lk = (b0 >> 2) & 3;

    for (int c = t; c < 2560; c += 256) {
        int n   = c / 80;
        int rem = c - n * 80;
        int p   = rem >> 4;
        int lm  = rem & 15;
        size_t idx = ((((size_t)n * 128 + rw) * 2 + mt) * 5 + p) * 64 + lk * 16 + lm;
        bf16x8 v = __builtin_bit_cast(bf16x8, up[idx]);
#pragma unroll
        for (int j = 0; j < 8; ++j) {
            int ct = 2 * p + (j >> 2);
            int rr = j & 3;
            ul[rr][n * STR2 + ct * 16 + lm] = v[j];
        }
    }
    const int grp = t >> 6;
    const int g   = t & 63;
    for (int pp = g; pp < IN_CAPS * OUT_CAPS; pp += 64) bl[grp][pp] = bbias[pp];
    __syncthreads();

    for (int it = 0; it < 4; ++it) {
        if (it > 0) {
            for (int pp = g; pp < IN_CAPS * OUT_CAPS; pp += 64) {
                int n = pp & 31;
                int o = pp >> 5;
                float a = 0.f;
#pragma unroll
                for (int d = 0; d < 16; ++d)
                    a += (float)ul[grp][n * STR2 + o * 16 + d] * vs[grp][o * 16 + d];
                bl[grp][n * 10 + o] += a;
            }
            __syncthreads();
        }
        if (g < IN_CAPS) {
            float m = bl[grp][g * 10];
#pragma unroll
            for (int o = 1; o < 10; ++o) m = fmaxf(m, bl[grp][g * 10 + o]);
            float e[10];
            float sum = 0.f;
#pragma unroll
            for (int o = 0; o < 10; ++o) { e[o] = __expf(bl[grp][g * 10 + o] - m); sum += e[o]; }
            float inv = 1.0f / sum;
#pragma unroll
            for (int o = 0; o < 10; ++o) cs[grp][g * 10 + o] = e[o] * inv;
        }
        __syncthreads();
        for (int p = g; p < NOUT; p += 64) {
            int o = p >> 4;
            float a = 0.f;
#pragma unroll
            for (int nn = 0; nn < IN_CAPS; ++nn)
                a += cs[grp][nn * 10 + o] * (float)ul[grp][nn * STR2 + p];
            ss[grp][p] = a;
        }
        __syncthreads();
        if (g < OUT_CAPS) {
            float sq = 0.f;
#pragma unroll
            for (int d = 0; d < 16; ++d) { float x = ss[grp][g * 16 + d]; sq += x * x; }
            scale_s[grp][g] = sq / ((1.0f + sq) * sqrtf(sq));
        }
        __syncthreads();
        for (int p = g; p < NOUT; p += 64) vs[grp][p] = scale_s[grp][p >> 4] * ss[grp][p];
        __syncthreads();
    }

    for (int p = g; p < NOUT; p += 64)
        out[(size_t)(b0 + grp) * NOUT + p] = vs[grp][p];
}

// ---------------------------------------------------------------------------
extern "C" void kernel_launch(void* const* d_in, const int* in_sizes, int n_in,
                              void* d_out, int out_size, void* d_ws, size_t ws_size,
                              hipStream_t stream) {
    const float* caps  = (const float*)d_in[0];   // [4096][32][288]
    const float* W     = (const float*)d_in[1];   // [32][288][160]
    const float* bbias = (const float*)d_in[2];   // [32][10]
    float* out = (float*)d_out;                   // [4096][10][16]

    __bf16* Wf = (__bf16*)d_ws;                               // 2,949,120 B
    uint4*  up = (uint4*)((char*)d_ws + 2949120);             // 41,943,040 B

    prep_w<<<dim3(5760), dim3(256), 0, stream>>>(W, Wf);
    gemm_u<<<dim3(512), dim3(512), 0, stream>>>(caps, Wf, up);
    routing<<<dim3(BATCH / 4), dim3(256), 0, stream>>>(up, bbias, out);
}